// Round 2
// baseline (1031.132 us; speedup 1.0000x reference)
//
#include <hip/hip_runtime.h>
#include <hip/hip_bf16.h>

// out[b,s,h] = sum_d x[b,s,d] * W[cat[b],d,h] + bias[cat[b],h]
// x: [64,512,1024] f32, cat_ids: [64] int, W: [16,1024,4096] f32, bias: [16,4096] f32

#define SEQ 512
#define DIN 1024
#define DH  4096

#define BM 256
#define BN 256
#define BK 64
#define NT 512   // 8 waves: 2 (M) x 4 (N); each wave owns 128x64 of C

typedef __attribute__((ext_vector_type(8))) short  short8;   // 8 bf16 = MFMA A/B frag
typedef __attribute__((ext_vector_type(4))) float  f32x4;
typedef __attribute__((ext_vector_type(4))) __bf16 bf16x4;

// XOR swizzle within a 128-byte LDS row: spreads 16-lane stride-128B frag
// reads (otherwise all bank 0) across 8 x 16B bank groups. Verified R1.
static __device__ __forceinline__ int swz(int row) {
    return ((row ^ (row >> 3)) & 7) << 4;
}

__global__ __launch_bounds__(NT, 2)
void cat_lin_mfma(const float* __restrict__ x,
                  const int*   __restrict__ cat_ids,
                  const float* __restrict__ W,
                  const float* __restrict__ bias,
                  float*       __restrict__ out) {
    // A: x-tile [m][k] bf16, rows 128B, swizzled. B: W-tile transposed [n][k].
    // Double-buffered: 4 x 32 KB = 128 KB LDS -> 1 block/CU, 2 waves/SIMD.
    __shared__ __align__(16) unsigned char lA[2][BM * BK * 2];
    __shared__ __align__(16) unsigned char lB[2][BN * BK * 2];

    const int t    = threadIdx.x;
    const int lane = t & 63;
    const int wave = t >> 6;
    const int wm   = (wave >> 2) * 128;   // wave row offset in tile (2 m-waves)
    const int wn   = (wave & 3) * 64;     // wave col offset in tile (4 n-waves)
    const int l15  = lane & 15;
    const int lg   = lane >> 4;

    const int nb    = blockIdx.x * BN;
    const int mbase = blockIdx.y * BM;
    const int bb    = blockIdx.z;
    const int c     = cat_ids[bb];

    const float* xp = x + (size_t)bb * SEQ * DIN + (size_t)mbase * DIN;
    const float* wp = W + (size_t)c * DIN * DH + nb;

    f32x4 acc[8][4];
    #pragma unroll
    for (int i = 0; i < 8; i++)
        #pragma unroll
        for (int j = 0; j < 4; j++)
            acc[i][j] = (f32x4)0.f;

    // staging coordinates
    const int aM = t >> 4;            // A: rows aM + 32*i, 16 threads/row
    const int aK = (t & 15) * 4;      // A: k quad (float4 along k)
    const int bN = (t & 63) * 4;      // B: n quad (float4 along n, coalesced)
    const int bK = (t >> 6) * 4;      // B: k rows bK + 32*i .. +3

    f32x4 va[8], vb[8];               // in-flight f32 staging registers

    auto loadA = [&](int kt) {
        #pragma unroll
        for (int i = 0; i < 8; i++)
            va[i] = *(const f32x4*)(xp + (size_t)(aM + i * 32) * DIN + kt + aK);
    };
    auto loadB = [&](int kt) {
        #pragma unroll
        for (int i = 0; i < 2; i++) {
            const int k0 = bK + i * 32;
            const float* wr = wp + (size_t)(kt + k0) * DH + bN;
            #pragma unroll
            for (int r = 0; r < 4; r++)
                vb[i * 4 + r] = *(const f32x4*)(wr + (size_t)r * DH);
        }
    };
    auto writeA = [&](int buf) {
        #pragma unroll
        for (int i = 0; i < 8; i++) {
            const int m = aM + i * 32;
            bf16x4 h;
            h[0] = (__bf16)va[i][0]; h[1] = (__bf16)va[i][1];
            h[2] = (__bf16)va[i][2]; h[3] = (__bf16)va[i][3];
            *(bf16x4*)(&lA[buf][m * (BK * 2) + ((aK * 2) ^ swz(m))]) = h;
        }
    };
    auto writeB = [&](int buf) {      // 4x4 register transpose -> k-contiguous
        #pragma unroll
        for (int i = 0; i < 2; i++) {
            const int k0 = bK + i * 32;
            #pragma unroll
            for (int jj = 0; jj < 4; jj++) {
                bf16x4 h;
                h[0] = (__bf16)vb[i * 4 + 0][jj]; h[1] = (__bf16)vb[i * 4 + 1][jj];
                h[2] = (__bf16)vb[i * 4 + 2][jj]; h[3] = (__bf16)vb[i * 4 + 3][jj];
                const int n = bN + jj;
                *(bf16x4*)(&lB[buf][n * (BK * 2) + ((k0 * 2) ^ swz(n))]) = h;
            }
        }
    };
    auto phase = [&](int cur_, int ks) {   // one ks=32 slice: 12 ds_read + 32 MFMA
        const int kb = ks * 64 + lg * 16;
        short8 bfv[4];
        #pragma unroll
        for (int fn = 0; fn < 4; fn++) {
            const int n = wn + fn * 16 + l15;
            bfv[fn] = *(const short8*)(&lB[cur_][n * (BK * 2) + (kb ^ swz(n))]);
        }
        __builtin_amdgcn_s_setprio(1);
        #pragma unroll
        for (int fm = 0; fm < 8; fm++) {
            const int m = wm + fm * 16 + l15;
            const short8 af = *(const short8*)(&lA[cur_][m * (BK * 2) + (kb ^ swz(m))]);
            #pragma unroll
            for (int fn = 0; fn < 4; fn++)
                acc[fm][fn] = __builtin_amdgcn_mfma_f32_16x16x32_bf16(
                    af, bfv[fn], acc[fm][fn], 0, 0, 0);
        }
        __builtin_amdgcn_s_setprio(0);
    };

    // prologue: stage tile 0 into buf 0
    loadA(0); loadB(0);
    writeA(0); writeB(0);
    __syncthreads();

    int cur = 0;
    for (int kt = 0; kt < DIN; kt += BK) {
        const bool pf = (kt + BK) < DIN;
        if (pf) { loadA(kt + BK); loadB(kt + BK); }  // issue early (T14)
        phase(cur, 0);                               // MFMA hides load latency
        if (pf) writeA(cur ^ 1);                     // counted vmcnt (va only)
        phase(cur, 1);
        if (pf) writeB(cur ^ 1);
        __syncthreads();                             // single barrier per K-step
        cur ^= 1;
    }

    // epilogue: D[row = lg*4 + r][col = l15] per 16x16 frag (verified R1)
    const float* bp = bias + (size_t)c * DH;
    float*       op = out + (size_t)bb * SEQ * DH;
    #pragma unroll
    for (int fn = 0; fn < 4; fn++) {
        const int col = nb + wn + fn * 16 + l15;
        const float bv = bp[col];
        #pragma unroll
        for (int fm = 0; fm < 8; fm++) {
            const int row0 = mbase + wm + fm * 16 + lg * 4;
            #pragma unroll
            for (int r = 0; r < 4; r++)
                op[(size_t)(row0 + r) * DH + col] = acc[fm][fn][r] + bv;
        }
    }
}

extern "C" void kernel_launch(void* const* d_in, const int* in_sizes, int n_in,
                              void* d_out, int out_size, void* d_ws, size_t ws_size,
                              hipStream_t stream) {
    const float* x   = (const float*)d_in[0];
    const int*   cid = (const int*)d_in[1];
    const float* W   = (const float*)d_in[2];
    const float* b   = (const float*)d_in[3];
    float*       out = (float*)d_out;

    dim3 grid(DH / BN, SEQ / BM, 64);   // 16 x 2 x 64 = 2048 blocks (~1/CU resident)
    dim3 block(NT);
    cat_lin_mfma<<<grid, block, 0, stream>>>(x, cid, W, b, out);
}

// Round 3
// 483.576 us; speedup vs baseline: 2.1323x; 2.1323x over previous
//
#include <hip/hip_runtime.h>
#include <hip/hip_bf16.h>

// out[b,s,h] = sum_d x[b,s,d] * W[cat[b],d,h] + bias[cat[b],h]
// x: [64,512,1024] f32, cat_ids: [64] int, W: [16,1024,4096] f32, bias: [16,4096] f32
//
// Strategy: prepass casts x -> bf16 [B][S][K] and W -> bf16 TRANSPOSED [C][N][K]
// in d_ws (201.3 MB), then a m97-structure bf16 B^T GEMM with global_load_lds
// + both-sides XOR swizzle. Fallback (ws too small): R1 fused kernel.

#define SEQ 512
#define DIN 1024
#define DH  4096
#define NCAT 16
#define NB   64

typedef __attribute__((ext_vector_type(8))) short   short8;
typedef __attribute__((ext_vector_type(8))) __bf16  bf16x8;
typedef __attribute__((ext_vector_type(4))) __bf16  bf16x4;
typedef __attribute__((ext_vector_type(4))) float   f32x4;

static __device__ __forceinline__ void gload_lds16(const void* g, void* l) {
    __builtin_amdgcn_global_load_lds(
        (const __attribute__((address_space(1))) void*)g,
        (__attribute__((address_space(3))) void*)l,
        16, 0, 0);
}

// ---------------- prepass 1: x f32 -> bf16 (flat cast) ----------------
__global__ __launch_bounds__(256)
void conv_x(const float* __restrict__ x, __bf16* __restrict__ xb, int n8) {
    int idx = blockIdx.x * 256 + threadIdx.x;
    const int stride = gridDim.x * 256;
    for (; idx < n8; idx += stride) {
        const f32x4 a = ((const f32x4*)x)[(size_t)idx * 2];
        const f32x4 b = ((const f32x4*)x)[(size_t)idx * 2 + 1];
        bf16x8 h;
        h[0]=(__bf16)a[0]; h[1]=(__bf16)a[1]; h[2]=(__bf16)a[2]; h[3]=(__bf16)a[3];
        h[4]=(__bf16)b[0]; h[5]=(__bf16)b[1]; h[6]=(__bf16)b[2]; h[7]=(__bf16)b[3];
        ((bf16x8*)xb)[idx] = h;
    }
}

// ------- prepass 2: W [C][K][N] f32 -> Wt [C][N][K] bf16 (LDS transpose) -------
__global__ __launch_bounds__(256)
void conv_w(const float* __restrict__ W, __bf16* __restrict__ wt) {
    __shared__ float lt[64][65];            // pad 65: write 2-way, read 2-way
    const int t  = threadIdx.x;
    const int nb = blockIdx.x * 64;
    const int kb = blockIdx.y * 64;
    const int c  = blockIdx.z;
    #pragma unroll
    for (int p = 0; p < 4; p++) {
        const int row = (t >> 4) + p * 16;          // k within tile
        const int col = (t & 15) * 4;               // n within tile
        const f32x4 v = *(const f32x4*)(W + ((size_t)c * DIN + kb + row) * DH + nb + col);
        lt[row][col] = v[0]; lt[row][col+1] = v[1];
        lt[row][col+2] = v[2]; lt[row][col+3] = v[3];
    }
    __syncthreads();
    #pragma unroll
    for (int p = 0; p < 2; p++) {
        const int n  = (t >> 3) + p * 32;
        const int k0 = (t & 7) * 8;
        bf16x8 h;
        #pragma unroll
        for (int j = 0; j < 8; j++) h[j] = (__bf16)lt[k0 + j][n];
        *(bf16x8*)(wt + ((size_t)c * DH + nb + n) * DIN + kb + k0) = h;
    }
}

// ---------------- main GEMM: m97 structure, 128x128, BK=64 ----------------
// LDS slot (row, g) holds elements (row, g ^ (row&7)) (g = 16B group, 8/row).
// Staged by inverse-permuting the per-lane GLOBAL address (rule #21);
// read back with the same XOR -> conflict-free stride-128B fragment reads.
__global__ __launch_bounds__(256, 2)
void gemm_bt(const __bf16* __restrict__ xb, const int* __restrict__ cat_ids,
             const __bf16* __restrict__ wt, const float* __restrict__ bias,
             float* __restrict__ out) {
    __shared__ __align__(16) __bf16 lA[128 * 64];   // 16 KB
    __shared__ __align__(16) __bf16 lB[128 * 64];   // 16 KB

    const int t    = threadIdx.x;
    const int lane = t & 63;
    const int w    = t >> 6;
    const int wm   = (w >> 1) * 64;
    const int wn   = (w & 1) * 64;
    const int l15  = lane & 15;
    const int lg   = lane >> 4;

    const int nb = blockIdx.x * 128;
    const int mb = blockIdx.y * 128;
    const int bb = blockIdx.z;
    const int c  = cat_ids[bb];

    const __bf16* xp = xb + ((size_t)bb * SEQ + mb) * DIN;
    const __bf16* wp = wt + ((size_t)c * DH + nb) * DIN;

    // staging: chunk q = w*4+i covers rows q*8 .. q*8+7; lane>>3 = row&7.
    // swizzled source column group: (lane&7) ^ (lane>>3).
    const int srow = lane >> 3;
    const int scol = ((lane & 7) ^ (lane >> 3)) * 8;

    f32x4 acc[4][4];
    #pragma unroll
    for (int i = 0; i < 4; i++)
        #pragma unroll
        for (int j = 0; j < 4; j++) acc[i][j] = (f32x4)0.f;

    for (int kt = 0; kt < DIN; kt += 64) {
        #pragma unroll
        for (int i = 0; i < 4; i++) {
            const int q = w * 4 + i;
            const int r = q * 8 + srow;
            gload_lds16(xp + (size_t)r * DIN + kt + scol, &lA[q * 512]);
            gload_lds16(wp + (size_t)r * DIN + kt + scol, &lB[q * 512]);
        }
        __syncthreads();   // drains vmcnt(0): tiles resident + visible

        #pragma unroll
        for (int ks = 0; ks < 2; ks++) {
            const int kob = (ks * 32 + lg * 8) * 2;        // byte offset of group
            short8 bfv[4];
            #pragma unroll
            for (int fn = 0; fn < 4; fn++) {
                const int n = wn + fn * 16 + l15;
                bfv[fn] = *(const short8*)((const char*)lB +
                            (n * 128 + (kob ^ ((n & 7) << 4))));
            }
            #pragma unroll
            for (int fm = 0; fm < 4; fm++) {
                const int m = wm + fm * 16 + l15;
                const short8 af = *(const short8*)((const char*)lA +
                            (m * 128 + (kob ^ ((m & 7) << 4))));
                #pragma unroll
                for (int fn = 0; fn < 4; fn++)
                    acc[fm][fn] = __builtin_amdgcn_mfma_f32_16x16x32_bf16(
                        af, bfv[fn], acc[fm][fn], 0, 0, 0);
            }
        }
        __syncthreads();   // reads done before next stage overwrites
    }

    const float* bp = bias + (size_t)c * DH;
    float*       op = out + (size_t)bb * SEQ * DH;
    #pragma unroll
    for (int fn = 0; fn < 4; fn++) {
        const int col = nb + wn + fn * 16 + l15;
        const float bv = bp[col];
        #pragma unroll
        for (int fm = 0; fm < 4; fm++) {
            const int row0 = mb + wm + fm * 16 + lg * 4;
            #pragma unroll
            for (int r = 0; r < 4; r++)
                op[(size_t)(row0 + r) * DH + col] = acc[fm][fn][r] + bv;
        }
    }
}

// ---------------- fallback (ws too small): R1 fused kernel ----------------
static __device__ __forceinline__ int swz_fb(int row) {
    return ((row ^ (row >> 3)) & 7) << 4;
}
__global__ __launch_bounds__(256, 2)
void cat_lin_fb(const float* __restrict__ x, const int* __restrict__ cat_ids,
                const float* __restrict__ W, const float* __restrict__ bias,
                float* __restrict__ out) {
    __shared__ unsigned char lA[128 * 64 * 2];
    __shared__ unsigned char lB[128 * 64 * 2];
    const int t = threadIdx.x, lane = t & 63, wave = t >> 6;
    const int wm = (wave >> 1) * 64, wn = (wave & 1) * 64;
    const int l15 = lane & 15, lg = lane >> 4;
    const int nb = blockIdx.x * 128, mb = blockIdx.y * 128, bb = blockIdx.z;
    const int c = cat_ids[bb];
    const float* xp = x + (size_t)bb * SEQ * DIN + (size_t)mb * DIN;
    const float* wp = W + (size_t)c * DIN * DH + nb;
    f32x4 acc[4][4];
    #pragma unroll
    for (int i = 0; i < 4; i++)
        #pragma unroll
        for (int j = 0; j < 4; j++) acc[i][j] = (f32x4)0.f;
    const int aM = t >> 4, aK = (t & 15) * 4;
    const int bN = (t & 31) * 4, bK = (t >> 5) * 4;
    for (int kt = 0; kt < DIN; kt += 64) {
        #pragma unroll
        for (int i = 0; i < 8; i++) {
            const int m = aM + i * 16;
            const f32x4 v = *(const f32x4*)(xp + (size_t)m * DIN + kt + aK);
            bf16x4 h;
            h[0]=(__bf16)v[0]; h[1]=(__bf16)v[1]; h[2]=(__bf16)v[2]; h[3]=(__bf16)v[3];
            *(bf16x4*)(&lA[m * 128 + ((aK * 2) ^ swz_fb(m))]) = h;
        }
        #pragma unroll
        for (int i = 0; i < 2; i++) {
            const int k0 = bK + i * 32;
            const float* wr = wp + (size_t)(kt + k0) * DH + bN;
            const f32x4 r0 = *(const f32x4*)(wr);
            const f32x4 r1 = *(const f32x4*)(wr + DH);
            const f32x4 r2 = *(const f32x4*)(wr + 2 * (size_t)DH);
            const f32x4 r3 = *(const f32x4*)(wr + 3 * (size_t)DH);
            #pragma unroll
            for (int jj = 0; jj < 4; jj++) {
                bf16x4 h;
                h[0]=(__bf16)r0[jj]; h[1]=(__bf16)r1[jj];
                h[2]=(__bf16)r2[jj]; h[3]=(__bf16)r3[jj];
                const int n = bN + jj;
                *(bf16x4*)(&lB[n * 128 + ((k0 * 2) ^ swz_fb(n))]) = h;
            }
        }
        __syncthreads();
        #pragma unroll
        for (int ks = 0; ks < 2; ks++) {
            const int kb2 = ks * 64 + lg * 16;
            short8 bfv[4];
            #pragma unroll
            for (int fn = 0; fn < 4; fn++) {
                const int n = wn + fn * 16 + l15;
                bfv[fn] = *(const short8*)(&lB[n * 128 + (kb2 ^ swz_fb(n))]);
            }
            #pragma unroll
            for (int fm = 0; fm < 4; fm++) {
                const int m = wm + fm * 16 + l15;
                const short8 af = *(const short8*)(&lA[m * 128 + (kb2 ^ swz_fb(m))]);
                #pragma unroll
                for (int fn = 0; fn < 4; fn++)
                    acc[fm][fn] = __builtin_amdgcn_mfma_f32_16x16x32_bf16(
                        af, bfv[fn], acc[fm][fn], 0, 0, 0);
            }
        }
        __syncthreads();
    }
    const float* bp = bias + (size_t)c * DH;
    float* op = out + (size_t)bb * SEQ * DH;
    #pragma unroll
    for (int fn = 0; fn < 4; fn++) {
        const int col = nb + wn + fn * 16 + l15;
        const float bv = bp[col];
        #pragma unroll
        for (int fm = 0; fm < 4; fm++) {
            const int row0 = mb + wm + fm * 16 + lg * 4;
            #pragma unroll
            for (int r = 0; r < 4; r++)
                op[(size_t)(row0 + r) * DH + col] = acc[fm][fn][r] + bv;
        }
    }
}

extern "C" void kernel_launch(void* const* d_in, const int* in_sizes, int n_in,
                              void* d_out, int out_size, void* d_ws, size_t ws_size,
                              hipStream_t stream) {
    const float* x   = (const float*)d_in[0];
    const int*   cid = (const int*)d_in[1];
    const float* W   = (const float*)d_in[2];
    const float* b   = (const float*)d_in[3];
    float*       out = (float*)d_out;

    const size_t xb_bytes = (size_t)NB * SEQ * DIN * 2;    // 67,108,864
    const size_t wt_bytes = (size_t)NCAT * DH * DIN * 2;   // 134,217,728

    if (ws_size >= xb_bytes + wt_bytes) {
        __bf16* xbuf = (__bf16*)d_ws;
        __bf16* wbuf = (__bf16*)((char*)d_ws + xb_bytes);
        conv_x<<<2048, 256, 0, stream>>>(x, xbuf, NB * SEQ * DIN / 8);
        dim3 gw(DH / 64, DIN / 64, NCAT);                  // 64 x 16 x 16
        conv_w<<<gw, 256, 0, stream>>>(W, wbuf);
        dim3 gg(DH / 128, SEQ / 128, NB);                  // 32 x 4 x 64
        gemm_bt<<<gg, 256, 0, stream>>>(xbuf, cid, wbuf, b, out);
    } else {
        dim3 gg(DH / 128, SEQ / 128, NB);
        cat_lin_fb<<<gg, 256, 0, stream>>>(x, cid, W, b, out);
    }
}